// Round 8
// baseline (177.469 us; speedup 1.0000x reference)
//
#include <hip/hip_runtime.h>
#include <hip/hip_bf16.h>

#define B_SZ 8
#define T_SZ 1024
#define D_IN 512
#define D_H  64
#define N_H  8

typedef __hip_bfloat16 bf16;
using short8  = __attribute__((ext_vector_type(8))) short;
using short4v = __attribute__((ext_vector_type(4))) short;
using f32x4   = __attribute__((ext_vector_type(4))) float;

__device__ __forceinline__ unsigned short f2bf(float f) {
    union { __hip_bfloat16 b; unsigned short u; } c;
    c.b = __float2bfloat16(f);
    return c.u;
}

// global -> LDS direct copy, 16 B per lane. LDS dest = wave-uniform base +
// lane*16 (linear); global src is per-lane.
__device__ __forceinline__ void glds16(const unsigned short* g, unsigned short* l) {
    __builtin_amdgcn_global_load_lds(
        (const __attribute__((address_space(1))) unsigned int*)g,
        (__attribute__((address_space(3))) unsigned int*)l, 16, 0, 0);
}

// ---------------------------------------------------------------------------
// Weight transpose: W[i(k)][d][h] fp32 -> Wt[mat][c][k'] bf16, c = h*64+d,
// with k PRE-SWIZZLED within each 64-chunk: k' = (k&~63)|((k&63)^((c&7)<<3)).
// proj stages Wt with linear global_load_lds and applies the same XOR on its
// frag reads. EXACT round-6 text.
// ---------------------------------------------------------------------------
__global__ __launch_bounds__(256) void wt_kernel(
    const float* __restrict__ Wk, const float* __restrict__ Wq,
    const float* __restrict__ Wv, unsigned short* __restrict__ Wt)
{
    const int mat = blockIdx.y;
    const float* W = (mat == 0) ? Wk : (mat == 1) ? Wq : Wv;
    int idx = blockIdx.x * 256 + threadIdx.x;      // over 512*512
    float v = W[idx];
    int k = idx >> 9, c = idx & 511;               // c = d*8 + h
    int h = c & 7, d = c >> 3;
    int ks = (k & ~63) | ((k & 63) ^ ((d & 7) << 3));
    Wt[(((size_t)mat * 8 + h) * 64 + d) * 512 + ks] = f2bf(v);
}

// ---------------------------------------------------------------------------
// MFMA projection, v6: A-from-global fp32 with in-register convert.
//   C[m][c] = sum_k X[m][k] * Wt[mat][c][k],  M=8192, N=512, K=512.
//   grid (64,4,3), 128x128 tile, 4 waves 2x2, wave 64x64, acc[4][4].
//   - X: NO LDS, NO staging pass. Each lane loads its A-frag (8 fp32 = two
//     float4 at [m0+wr+mt*16+l15][k0+ic*32+quad*8]) and converts in-register.
//     4 n0-sharers of an X panel are on the same XCD (ids differ by 64) ->
//     re-reads are L2/L3 hits.
//   - W: glds into TRIPLE-buffered Wst (3x16 KB), depth-2 prefetch.
//     Step kc: s_waitcnt vmcnt(4) (retire glds(kc), keep glds(kc+1) in
//     flight) -> s_barrier -> issue glds(kc+2) -> compute from Wst[kc%3].
//     WAR safe: Wst[(kc+2)%3]'s readers (step kc-1) retired before this
//     step's barrier. NO wave LDS writes anywhere; ONE barrier per step.
//   LDS 48 KB, 3 blocks/CU.
// ---------------------------------------------------------------------------
__global__ __launch_bounds__(256, 3) void proj_kernel(
    const float* __restrict__ keys, const float* __restrict__ queries,
    const float* __restrict__ values,
    const unsigned short* __restrict__ Wt, unsigned short* __restrict__ KQVb)
{
    const int tid = threadIdx.x;
    const int m0  = blockIdx.x * 128;
    const int n0  = blockIdx.y * 128;
    const int mat = blockIdx.z;

    const float* X = (mat == 0) ? keys : (mat == 1) ? queries : values;
    const unsigned short* WT = Wt + (size_t)mat * (512 * 512);   // [c][k'] swz
    unsigned short* P = KQVb + (size_t)mat * ((size_t)B_SZ * N_H * T_SZ * D_H);

    __shared__ __align__(16) unsigned short Wst[3][128 * 64];

    const int wid = tid >> 6, lane = tid & 63;
    const int quad = lane >> 4, l15 = lane & 15;
    const int wr = (wid >> 1) * 64, wc = (wid & 1) * 64;   // wave sub-tile

    // W glds coords: unit = wid*4+q -> rows wid*32+q*8 + (lane>>3), chunk lane&7
    const int wrow  = wid * 32 + (lane >> 3);
    const int wcol8 = (lane & 7) * 8;
    // A row base for this lane (mt*16 added per fragment)
    const int arow = m0 + wr + l15;

    f32x4 acc[4][4];
    #pragma unroll
    for (int i = 0; i < 4; ++i)
        #pragma unroll
        for (int n = 0; n < 4; ++n) acc[i][n] = (f32x4){0.f, 0.f, 0.f, 0.f};

    // ---- prologue: issue glds for K-tiles 0 and 1 ----
    #pragma unroll
    for (int q = 0; q < 4; ++q)
        glds16(&WT[(size_t)(n0 + wrow + q * 8) * 512 + wcol8],
               &Wst[0][(wid * 4 + q) * 512]);
    #pragma unroll
    for (int q = 0; q < 4; ++q)
        glds16(&WT[(size_t)(n0 + wrow + q * 8) * 512 + 64 + wcol8],
               &Wst[1][(wid * 4 + q) * 512]);

    for (int kc = 0; kc < 8; ++kc) {
        const int k0 = kc * 64;
        // retire glds(kc); glds(kc+1) stays in flight
        if (kc < 7) asm volatile("s_waitcnt vmcnt(4)" ::: "memory");
        else        asm volatile("s_waitcnt vmcnt(0)" ::: "memory");
        __builtin_amdgcn_s_barrier();
        // issue glds(kc+2) into the buffer read two steps ago
        if (kc < 6) {
            const int k2 = k0 + 128;
            #pragma unroll
            for (int q = 0; q < 4; ++q)
                glds16(&WT[(size_t)(n0 + wrow + q * 8) * 512 + k2 + wcol8],
                       &Wst[(kc + 2) % 3][(wid * 4 + q) * 512]);
        }
        __builtin_amdgcn_sched_barrier(0);

        const unsigned short* Wb = Wst[kc % 3];
        #pragma unroll
        for (int ic = 0; ic < 2; ++ic) {
            const int sc = ic * 32 + quad * 8;
            // A: direct fp32 loads + in-register convert
            short8 af[4];
            #pragma unroll
            for (int mt = 0; mt < 4; ++mt) {
                const float* ap = &X[(size_t)(arow + mt * 16) * 512 + k0 + sc];
                float4 a = *(const float4*)ap;
                float4 b = *(const float4*)(ap + 4);
                af[mt] = (short8){(short)f2bf(a.x), (short)f2bf(a.y),
                                  (short)f2bf(a.z), (short)f2bf(a.w),
                                  (short)f2bf(b.x), (short)f2bf(b.y),
                                  (short)f2bf(b.z), (short)f2bf(b.w)};
            }
            // B from LDS (XOR-swizzled)
            short8 bfr[4];
            #pragma unroll
            for (int nt = 0; nt < 4; ++nt) {
                int r = wc + nt * 16 + l15;
                bfr[nt] = *(const short8*)&Wb[r * 64 + (sc ^ ((r & 7) << 3))];
            }
            #pragma unroll
            for (int mt = 0; mt < 4; ++mt)
                #pragma unroll
                for (int nt = 0; nt < 4; ++nt)
                    acc[mt][nt] = __builtin_amdgcn_mfma_f32_16x16x32_bf16(
                        af[mt], bfr[nt], acc[mt][nt], 0, 0, 0);
        }
    }

    // epilogue: row m = m0+wr+mt*16+quad*4+r; col c = n0+wc+nt*16+l15
    #pragma unroll
    for (int mt = 0; mt < 4; ++mt)
        #pragma unroll
        for (int r = 0; r < 4; ++r) {
            int mrow = m0 + wr + mt * 16 + quad * 4 + r;
            int bb = mrow >> 10, t = mrow & 1023;
            #pragma unroll
            for (int nt = 0; nt < 4; ++nt) {
                int c = n0 + wc + nt * 16 + l15;
                int h = c >> 6, d = c & 63;
                P[(((size_t)(bb * N_H + h)) * T_SZ + t) * D_H + d] =
                    f2bf(acc[mt][nt][r]);
            }
        }
}

// ---------------------------------------------------------------------------
// MFMA flash attention, v2b. EXACT text of the round-6 passing kernel.
// ---------------------------------------------------------------------------
#define SCALE  0.18033688f      /* (1/sqrt(64)) * log2(e) */
#define MASKV -180.33688f       /* -1000 * SCALE          */

__global__ __launch_bounds__(512, 4) void attn_kernel(
    const unsigned short* __restrict__ Qb, const unsigned short* __restrict__ Kb,
    const unsigned short* __restrict__ Vb,
    const int* __restrict__ key_seq, float* __restrict__ out)
{
    const int tid  = threadIdx.x;
    const int bid  = blockIdx.x;
    const int pair = bid >> 6;              // 0..7
    const int b    = (bid >> 3) & 7;
    const int h    = bid & 7;               // == bid%8 -> XCD id
    const int wid  = tid >> 6, lane = tid & 63;
    const int quad = lane >> 4, l15 = lane & 15;

    __shared__ __align__(16) unsigned short Kst[2][64 * 72];
    __shared__ __align__(16) unsigned short VTst[2][64 * 72];
    __shared__ __align__(16) float spadf[2][64];
    __shared__ int tflags[16];

    const size_t bh = (size_t)(b * N_H + h) * T_SZ;

    // strip assignment: waves 0-3 -> long strip, waves 4-7 -> short strip
    const int strip_j0 = (wid < 4) ? (15 - pair) * 64 : pair * 64;
    const int j0w = strip_j0 + (wid & 3) * 16;
    const int jg  = j0w + l15;
    const int ntmax = 16 - pair;            // long strip needs tiles 0..ntmax-1

    // Q fragments straight from global (one-time; no LDS staging)
    short8 qf0 = *(const short8*)&Qb[(bh + jg) * D_H + quad * 8];
    short8 qf1 = *(const short8*)&Qb[(bh + jg) * D_H + 32 + quad * 8];

    // per-tile flags: bit0 = any valid key, bit1 = any padded key
    {
        int ka  = key_seq[b * T_SZ + wid * 64 + lane];
        int kb2 = key_seq[b * T_SZ + 512 + wid * 64 + lane];
        unsigned long long ba  = __ballot(ka  != -1);
        unsigned long long bb2 = __ballot(kb2 != -1);
        if (lane == 0) {
            tflags[wid]     = (ba  != 0ull ? 1 : 0) | (ba  != ~0ull ? 2 : 0);
            tflags[8 + wid] = (bb2 != 0ull ? 1 : 0) | (bb2 != ~0ull ? 2 : 0);
        }
    }

    // staging coordinates
    const int sk_row = tid >> 3, sk_c = tid & 7;        // K: 64 rows x 8 chunks
    const int sv_i = lane, sv_ch = wid;                  // V: col i, d-chunk ch
    // permuted V^T column: c = i3*16 + i2*8 + i4*4 + i1i0 (+ i5) so that the
    // MFMA contraction order equals the p[] register order
    const int sv_col = (sv_i & 3) | ((sv_i & 16) >> 2) | ((sv_i & 4) << 1)
                     | ((sv_i & 8) << 1) | (sv_i & 32);

    // issue tile-0 loads
    short8 kreg = *(const short8*)&Kb[(bh + sk_row) * D_H + sk_c * 8];
    short8 vreg = *(const short8*)&Vb[(bh + sv_i) * D_H + sv_ch * 8];
    int ksv = (tid < 64) ? key_seq[b * T_SZ + tid] : -1;

    __syncthreads();                        // tflags ready

    unsigned tmask = 1u, pmask = 0u;
    #pragma unroll
    for (int t = 0; t < 16; ++t) {
        int f = tflags[t];
        tmask |= (unsigned)(f & 1) << t;
        pmask |= (unsigned)((f >> 1) & 1) << t;
    }
    tmask &= (unsigned)((1ull << ntmax) - 1ull);
    tmask |= 1u;                            // tile 0 always processed

    // write tile 0 into buffer 0
    *(short8*)&Kst[0][sk_row * 72 + sk_c * 8] = kreg;
    #pragma unroll
    for (int e = 0; e < 8; ++e)
        VTst[0][(sv_ch * 8 + e) * 72 + sv_col] = (unsigned short)vreg[e];
    if (tid < 64) spadf[0][tid] = (ksv == -1) ? MASKV : 0.f;
    __syncthreads();

    float m = -1e30f, l = 0.f;
    f32x4 o0 = {0.f,0.f,0.f,0.f}, o1 = o0, o2 = o0, o3 = o0;

    unsigned rem = tmask & ~1u;
    int tcur = 0, nb = 0;
    for (;;) {
        // ---- issue next tile's global loads (latency hides under compute) ----
        int tnext = -1;
        if (rem) { tnext = __ffs((int)rem) - 1; rem &= rem - 1; }
        if (tnext >= 0) {
            const size_t r0 = bh + tnext * 64;
            kreg = *(const short8*)&Kb[(r0 + sk_row) * D_H + sk_c * 8];
            vreg = *(const short8*)&Vb[(r0 + sv_i) * D_H + sv_ch * 8];
            if (tid < 64) ksv = key_seq[b * T_SZ + tnext * 64 + tid];
        }

        // ---- compute tile tcur from buffer nb ----
        const int i0 = tcur * 64;
        if (i0 <= j0w + 15) {                           // wave has unmasked rows
            const bool haspad = (pmask >> tcur) & 1u;
            const bool needC  = (i0 + 63 > j0w);        // diagonal tile only
            float sv[16];
            #pragma unroll
            for (int it = 0; it < 4; ++it) {
                f32x4 s = {0.f,0.f,0.f,0.f};
                short8 a0 = *(const short8*)&Kst[nb][(it*16 + l15) * 72 + quad*8];
                s = __builtin_amdgcn_mfma_f32_16x16x32_bf16(a0, qf0, s, 0, 0, 0);
                short8 a1 = *(const short8*)&Kst[nb][(it*16 + l15) * 72 + 32 + quad*8];
                s = __builtin_amdgcn_mfma_f32_16x16x32_bf16(a1, qf1, s, 0, 0, 0);
                f32x4 sp = {0.f,0.f,0.f,0.f};
                if (haspad) sp = *(const f32x4*)&spadf[nb][it*16 + quad*4];
                #pragma unroll
                for (int r = 0; r < 4; ++r) {
                    float v = __builtin_fmaf(s[r], SCALE, sp[r]);
                    if (needC && (i0 + it*16 + quad*4 + r > jg)) v += MASKV;
                    sv[it*4 + r] = v;
                }
            }

            // online softmax over i (per j = l15; i spans regs + quads)
            float mt = sv[0];
            #pragma unroll
            for (int k = 1; k < 16; ++k) mt = fmaxf(mt, sv[k]);
            mt = fmaxf(mt, __shfl_xor(mt, 16));
            mt = fmaxf(mt, __shfl_xor(mt, 32));
            const float mnew  = fmaxf(m, mt);
            const float alpha = exp2f(m - mnew);
            float p[16], ls = 0.f;
            #pragma unroll
            for (int k = 0; k < 16; ++k) {
                p[k] = exp2f(sv[k] - mnew);
                ls += p[k];
            }
            ls += __shfl_xor(ls, 16);
            ls += __shfl_xor(ls, 32);
            l = l * alpha + ls;
            m = mnew;
            o0 *= alpha; o1 *= alpha; o2 *= alpha; o3 *= alpha;

            // PV B-frags directly from registers (V columns pre-permuted)
            short8 pf0, pf1;
            #pragma unroll
            for (int e = 0; e < 8; ++e) {
                pf0[e] = (short)f2bf(p[e]);
                pf1[e] = (short)f2bf(p[8 + e]);
            }
            short8 a;
            a = *(const short8*)&VTst[nb][(     l15) * 72 +      quad * 8];
            o0 = __builtin_amdgcn_mfma_f32_16x16x32_bf16(a, pf0, o0, 0, 0, 0);
            a = *(const short8*)&VTst[nb][(     l15) * 72 + 32 + quad * 8];
            o0 = __builtin_amdgcn_mfma_f32_16x16x32_bf16(a, pf1, o0, 0, 0, 0);
            a = *(const short8*)&VTst[nb][(16 + l15) * 72 +      quad * 8];
            o1 = __builtin_amdgcn_mfma_f32_16x16x32_bf16(a, pf0, o1, 0, 0, 0);
            a = *(const short8*)&VTst[nb][(16 + l15) * 72 + 32 + quad * 8];
            o1 = __builtin_amdgcn_mfma_f32_16x16x32_bf16(a, pf1, o1, 0, 0, 0);
            a = *(const short8*)&VTst[nb][(32 + l15) * 72 +      quad * 8];
            o2 = __builtin_amdgcn_mfma_f32_16x16x32_bf16(a, pf0, o2, 0, 0, 0);
            a = *(const short8*)&VTst[nb][(32 + l15) * 72 + 32 + quad * 8];
            o2 = __builtin_amdgcn_mfma_f32_16x16x32_bf16(a, pf1, o2, 0, 0, 0);
            a = *(const short8*)&VTst[nb][(48 + l15) * 72 +      quad * 8];
            o3 = __builtin_amdgcn_mfma_f32_16x16x32_bf16(a, pf0, o3, 0, 0, 0);
            a = *(const short8*)&VTst[nb][(48 + l15) * 72 + 32 + quad * 8];
            o3 = __builtin_amdgcn_mfma_f32_16x16x32_bf16(a, pf1, o3, 0, 0, 0);
        }

        if (tnext < 0) break;

        // ---- write next tile into the other buffer (T14 late-write) ----
        const int nb2 = nb ^ 1;
        *(short8*)&Kst[nb2][sk_row * 72 + sk_c * 8] = kreg;
        #pragma unroll
        for (int e = 0; e < 8; ++e)
            VTst[nb2][(sv_ch * 8 + e) * 72 + sv_col] = (unsigned short)vreg[e];
        if (tid < 64) spadf[nb2][tid] = (ksv == -1) ? MASKV : 0.f;
        __syncthreads();                     // single barrier per tile
        tcur = tnext; nb = nb2;
    }

    // epilogue: lane j = jg, d = dblk*16 + quad*4 + r -> float4 stores
    const float inv = 1.f / l;
    float* op = out + ((size_t)b * T_SZ + jg) * (N_H * D_H) + h * D_H + quad * 4;
    *(f32x4*)(op +  0) = o0 * inv;
    *(f32x4*)(op + 16) = o1 * inv;
    *(f32x4*)(op + 32) = o2 * inv;
    *(f32x4*)(op + 48) = o3 * inv;
}

// ---------------------------------------------------------------------------
extern "C" void kernel_launch(void* const* d_in, const int* in_sizes, int n_in,
                              void* d_out, int out_size, void* d_ws, size_t ws_size,
                              hipStream_t stream) {
    const float* keys    = (const float*)d_in[0];
    const float* queries = (const float*)d_in[1];
    const float* values  = (const float*)d_in[2];
    const float* Wk      = (const float*)d_in[3];
    const float* Wq      = (const float*)d_in[4];
    const float* Wv      = (const float*)d_in[5];
    const int*   key_seq = (const int*)d_in[6];

    const size_t per = (size_t)B_SZ * N_H * T_SZ * D_H;     // 4,194,304 elems
    unsigned short* KQVb = (unsigned short*)d_ws;            // K | Q | V bf16
    unsigned short* Kb = KQVb;
    unsigned short* Qb = KQVb + per;
    unsigned short* Vb = KQVb + 2 * per;
    unsigned short* Wt = KQVb + 3 * per;                     // 3*512*512 bf16

    wt_kernel<<<dim3(512 * 512 / 256, 3), 256, 0, stream>>>(Wk, Wq, Wv, Wt);
    proj_kernel<<<dim3(64, 4, 3), 256, 0, stream>>>(
        keys, queries, values, Wt, KQVb);
    attn_kernel<<<dim3(512), dim3(512), 0, stream>>>(
        Qb, Kb, Vb, key_seq, (float*)d_out);
}

// Round 9
// 153.801 us; speedup vs baseline: 1.1539x; 1.1539x over previous
//
#include <hip/hip_runtime.h>
#include <hip/hip_bf16.h>

#define B_SZ 8
#define T_SZ 1024
#define D_IN 512
#define D_H  64
#define N_H  8

typedef __hip_bfloat16 bf16;
using short8  = __attribute__((ext_vector_type(8))) short;
using short4v = __attribute__((ext_vector_type(4))) short;
using f32x4   = __attribute__((ext_vector_type(4))) float;

__device__ __forceinline__ unsigned short f2bf(float f) {
    union { __hip_bfloat16 b; unsigned short u; } c;
    c.b = __float2bfloat16(f);
    return c.u;
}

// global -> LDS direct copy, 16 B per lane. LDS dest = wave-uniform base +
// lane*16 (linear); global src is per-lane.
__device__ __forceinline__ void glds16(const unsigned short* g, unsigned short* l) {
    __builtin_amdgcn_global_load_lds(
        (const __attribute__((address_space(1))) unsigned int*)g,
        (__attribute__((address_space(3))) unsigned int*)l, 16, 0, 0);
}

// ---------------------------------------------------------------------------
// Weight transpose: W[i(k)][d][h] fp32 -> Wt[mat][c][k'] bf16, c = h*64+d,
// with k PRE-SWIZZLED within each 64-chunk: k' = (k&~63)|((k&63)^((c&7)<<3)).
// EXACT round-6 text.
// ---------------------------------------------------------------------------
__global__ __launch_bounds__(256) void wt_kernel(
    const float* __restrict__ Wk, const float* __restrict__ Wq,
    const float* __restrict__ Wv, unsigned short* __restrict__ Wt)
{
    const int mat = blockIdx.y;
    const float* W = (mat == 0) ? Wk : (mat == 1) ? Wq : Wv;
    int idx = blockIdx.x * 256 + threadIdx.x;      // over 512*512
    float v = W[idx];
    int k = idx >> 9, c = idx & 511;               // c = d*8 + h
    int h = c & 7, d = c >> 3;
    int ks = (k & ~63) | ((k & 63) ^ ((d & 7) << 3));
    Wt[(((size_t)mat * 8 + h) * 64 + d) * 512 + ks] = f2bf(v);
}

// ---------------------------------------------------------------------------
// MFMA projection, v4 (round-6 passing text, 35.5 us): counted-vmcnt pipeline.
//   Issue order per step: [X8 loads][sched_bar][G4 glds][sched_bar]; the
//   X-convert's implicit wait retires ONLY the X loads (in-order FIFO), and
//   s_waitcnt vmcnt(12) before barrier1 waits only for this step's W glds.
//   128x128 tile, 4 waves 2x2, acc[4][4], BK=64, Xst single + Wst double,
//   XOR-swizzled LDS, 48 KB, 3 blocks/CU.
// ---------------------------------------------------------------------------
__global__ __launch_bounds__(256, 3) void proj_kernel(
    const float* __restrict__ keys, const float* __restrict__ queries,
    const float* __restrict__ values,
    const unsigned short* __restrict__ Wt, unsigned short* __restrict__ KQVb)
{
    const int tid = threadIdx.x;
    const int m0  = blockIdx.x * 128;
    const int n0  = blockIdx.y * 128;
    const int mat = blockIdx.z;

    const float* X = (mat == 0) ? keys : (mat == 1) ? queries : values;
    const unsigned short* WT = Wt + (size_t)mat * (512 * 512);   // [c][k'] swizzled
    unsigned short* P = KQVb + (size_t)mat * ((size_t)B_SZ * N_H * T_SZ * D_H);

    __shared__ __align__(16) unsigned short Xst[128 * 64];
    __shared__ __align__(16) unsigned short Wst[2][128 * 64];

    const int wid = tid >> 6, lane = tid & 63;
    const int quad = lane >> 4, l15 = lane & 15;
    const int wr = (wid >> 1) * 64, wc = (wid & 1) * 64;   // wave sub-tile

    // X staging coords: unit u = tid + q*256 -> row = ur + q*32, chunk uch
    const int ur = tid >> 3, uch = tid & 7;
    // W glds coords: unit = wid*4+q -> rows wid*32+q*8 + (lane>>3), chunk lane&7
    const int wrow  = wid * 32 + (lane >> 3);
    const int wcol8 = (lane & 7) * 8;

    f32x4 acc[4][4];
    #pragma unroll
    for (int i = 0; i < 4; ++i)
        #pragma unroll
        for (int n = 0; n < 4; ++n) acc[i][n] = (f32x4){0.f, 0.f, 0.f, 0.f};

    const float4* X4 = (const float4*)X;

    // ---- prologue: X loads FIRST, glds SECOND (FIFO order matters) ----
    float4 xr[4][2];
    #pragma unroll
    for (int q = 0; q < 4; ++q) {
        int r = ur + q * 32;
        xr[q][0] = X4[(size_t)(m0 + r) * 128 + uch * 2];
        xr[q][1] = X4[(size_t)(m0 + r) * 128 + uch * 2 + 1];
    }
    __builtin_amdgcn_sched_barrier(0);
    #pragma unroll
    for (int q = 0; q < 4; ++q)
        glds16(&WT[(size_t)(n0 + wrow + q * 8) * 512 + wcol8],
               &Wst[0][(wid * 4 + q) * 512]);
    __builtin_amdgcn_sched_barrier(0);

    int wb = 0;
    for (int kc = 0; kc < 8; ++kc) {
        // ---- convert + write X: implicit wait retires X8(kc) only; the
        //      G4(kc) glds (younger in FIFO) stay outstanding ----
        #pragma unroll
        for (int q = 0; q < 4; ++q) {
            int r = ur + q * 32;
            float4 a = xr[q][0], b = xr[q][1];
            short8 s8 = {(short)f2bf(a.x), (short)f2bf(a.y),
                         (short)f2bf(a.z), (short)f2bf(a.w),
                         (short)f2bf(b.x), (short)f2bf(b.y),
                         (short)f2bf(b.z), (short)f2bf(b.w)};
            *(short8*)&Xst[r * 64 + ((uch * 8) ^ ((r & 7) << 3))] = s8;
        }
        // ---- prefetch step kc+1: X8 then G4, then counted wait for G4(kc) ----
        if (kc < 7) {
            const int k0n = (kc + 1) * 64;
            #pragma unroll
            for (int q = 0; q < 4; ++q) {
                int r = ur + q * 32;
                xr[q][0] = X4[(size_t)(m0 + r) * 128 + (k0n >> 2) + uch * 2];
                xr[q][1] = X4[(size_t)(m0 + r) * 128 + (k0n >> 2) + uch * 2 + 1];
            }
            __builtin_amdgcn_sched_barrier(0);
            #pragma unroll
            for (int q = 0; q < 4; ++q)
                glds16(&WT[(size_t)(n0 + wrow + q * 8) * 512 + k0n + wcol8],
                       &Wst[wb ^ 1][(wid * 4 + q) * 512]);
            __builtin_amdgcn_sched_barrier(0);
            // outstanding: G4(kc) + X8(kc+1) + G4(kc+1) = 16; keep 12 youngest
            asm volatile("s_waitcnt vmcnt(12)" ::: "memory");
        } else {
            asm volatile("s_waitcnt vmcnt(0)" ::: "memory");
        }
        __builtin_amdgcn_sched_barrier(0);
        // ---- barrier 1: LDS writes visible; prefetch stays in flight ----
        asm volatile("s_waitcnt lgkmcnt(0)" ::: "memory");
        __builtin_amdgcn_s_barrier();

        // ---- MFMA on Xst / Wst[wb] ----
        #pragma unroll
        for (int ic = 0; ic < 2; ++ic) {
            const int sc = ic * 32 + quad * 8;
            short8 af[4], bfr[4];
            #pragma unroll
            for (int mt = 0; mt < 4; ++mt) {
                int r = wr + mt * 16 + l15;
                af[mt] = *(const short8*)&Xst[r * 64 + (sc ^ ((r & 7) << 3))];
            }
            #pragma unroll
            for (int nt = 0; nt < 4; ++nt) {
                int r = wc + nt * 16 + l15;
                bfr[nt] = *(const short8*)&Wst[wb][r * 64 + (sc ^ ((r & 7) << 3))];
            }
            #pragma unroll
            for (int mt = 0; mt < 4; ++mt)
                #pragma unroll
                for (int nt = 0; nt < 4; ++nt)
                    acc[mt][nt] = __builtin_amdgcn_mfma_f32_16x16x32_bf16(
                        af[mt], bfr[nt], acc[mt][nt], 0, 0, 0);
        }

        // ---- barrier 2: frag reads retired before next step's X overwrite ----
        asm volatile("s_waitcnt lgkmcnt(0)" ::: "memory");
        __builtin_amdgcn_s_barrier();
        wb ^= 1;
    }

    // epilogue: row m = m0+wr+mt*16+quad*4+r; col c = n0+wc+nt*16+l15
    #pragma unroll
    for (int mt = 0; mt < 4; ++mt)
        #pragma unroll
        for (int r = 0; r < 4; ++r) {
            int mrow = m0 + wr + mt * 16 + quad * 4 + r;
            int bb = mrow >> 10, t = mrow & 1023;
            #pragma unroll
            for (int nt = 0; nt < 4; ++nt) {
                int c = n0 + wc + nt * 16 + l15;
                int h = c >> 6, d = c & 63;
                P[(((size_t)(bb * N_H + h)) * T_SZ + t) * D_H + d] =
                    f2bf(acc[mt][nt][r]);
            }
        }
}

// ---------------------------------------------------------------------------
// MFMA flash attention, v2c: round-6 passing structure + s_setprio(1) around
// the MFMA clusters (T5 -- 8 waves with phase-diverse strips, the regime
// where setprio measured +4-7%).
// ---------------------------------------------------------------------------
#define SCALE  0.18033688f      /* (1/sqrt(64)) * log2(e) */
#define MASKV -180.33688f       /* -1000 * SCALE          */

__global__ __launch_bounds__(512, 4) void attn_kernel(
    const unsigned short* __restrict__ Qb, const unsigned short* __restrict__ Kb,
    const unsigned short* __restrict__ Vb,
    const int* __restrict__ key_seq, float* __restrict__ out)
{
    const int tid  = threadIdx.x;
    const int bid  = blockIdx.x;
    const int pair = bid >> 6;              // 0..7
    const int b    = (bid >> 3) & 7;
    const int h    = bid & 7;               // == bid%8 -> XCD id
    const int wid  = tid >> 6, lane = tid & 63;
    const int quad = lane >> 4, l15 = lane & 15;

    __shared__ __align__(16) unsigned short Kst[2][64 * 72];
    __shared__ __align__(16) unsigned short VTst[2][64 * 72];
    __shared__ __align__(16) float spadf[2][64];
    __shared__ int tflags[16];

    const size_t bh = (size_t)(b * N_H + h) * T_SZ;

    // strip assignment: waves 0-3 -> long strip, waves 4-7 -> short strip
    const int strip_j0 = (wid < 4) ? (15 - pair) * 64 : pair * 64;
    const int j0w = strip_j0 + (wid & 3) * 16;
    const int jg  = j0w + l15;
    const int ntmax = 16 - pair;            // long strip needs tiles 0..ntmax-1

    // Q fragments straight from global (one-time; no LDS staging)
    short8 qf0 = *(const short8*)&Qb[(bh + jg) * D_H + quad * 8];
    short8 qf1 = *(const short8*)&Qb[(bh + jg) * D_H + 32 + quad * 8];

    // per-tile flags: bit0 = any valid key, bit1 = any padded key
    {
        int ka  = key_seq[b * T_SZ + wid * 64 + lane];
        int kb2 = key_seq[b * T_SZ + 512 + wid * 64 + lane];
        unsigned long long ba  = __ballot(ka  != -1);
        unsigned long long bb2 = __ballot(kb2 != -1);
        if (lane == 0) {
            tflags[wid]     = (ba  != 0ull ? 1 : 0) | (ba  != ~0ull ? 2 : 0);
            tflags[8 + wid] = (bb2 != 0ull ? 1 : 0) | (bb2 != ~0ull ? 2 : 0);
        }
    }

    // staging coordinates
    const int sk_row = tid >> 3, sk_c = tid & 7;        // K: 64 rows x 8 chunks
    const int sv_i = lane, sv_ch = wid;                  // V: col i, d-chunk ch
    // permuted V^T column: c = i3*16 + i2*8 + i4*4 + i1i0 (+ i5) so that the
    // MFMA contraction order equals the p[] register order
    const int sv_col = (sv_i & 3) | ((sv_i & 16) >> 2) | ((sv_i & 4) << 1)
                     | ((sv_i & 8) << 1) | (sv_i & 32);

    // issue tile-0 loads
    short8 kreg = *(const short8*)&Kb[(bh + sk_row) * D_H + sk_c * 8];
    short8 vreg = *(const short8*)&Vb[(bh + sv_i) * D_H + sv_ch * 8];
    int ksv = (tid < 64) ? key_seq[b * T_SZ + tid] : -1;

    __syncthreads();                        // tflags ready

    unsigned tmask = 1u, pmask = 0u;
    #pragma unroll
    for (int t = 0; t < 16; ++t) {
        int f = tflags[t];
        tmask |= (unsigned)(f & 1) << t;
        pmask |= (unsigned)((f >> 1) & 1) << t;
    }
    tmask &= (unsigned)((1ull << ntmax) - 1ull);
    tmask |= 1u;                            // tile 0 always processed

    // write tile 0 into buffer 0
    *(short8*)&Kst[0][sk_row * 72 + sk_c * 8] = kreg;
    #pragma unroll
    for (int e = 0; e < 8; ++e)
        VTst[0][(sv_ch * 8 + e) * 72 + sv_col] = (unsigned short)vreg[e];
    if (tid < 64) spadf[0][tid] = (ksv == -1) ? MASKV : 0.f;
    __syncthreads();

    float m = -1e30f, l = 0.f;
    f32x4 o0 = {0.f,0.f,0.f,0.f}, o1 = o0, o2 = o0, o3 = o0;

    unsigned rem = tmask & ~1u;
    int tcur = 0, nb = 0;
    for (;;) {
        // ---- issue next tile's global loads (latency hides under compute) ----
        int tnext = -1;
        if (rem) { tnext = __ffs((int)rem) - 1; rem &= rem - 1; }
        if (tnext >= 0) {
            const size_t r0 = bh + tnext * 64;
            kreg = *(const short8*)&Kb[(r0 + sk_row) * D_H + sk_c * 8];
            vreg = *(const short8*)&Vb[(r0 + sv_i) * D_H + sv_ch * 8];
            if (tid < 64) ksv = key_seq[b * T_SZ + tnext * 64 + tid];
        }

        // ---- compute tile tcur from buffer nb ----
        const int i0 = tcur * 64;
        if (i0 <= j0w + 15) {                           // wave has unmasked rows
            const bool haspad = (pmask >> tcur) & 1u;
            const bool needC  = (i0 + 63 > j0w);        // diagonal tile only
            float sv[16];
            __builtin_amdgcn_s_setprio(1);
            #pragma unroll
            for (int it = 0; it < 4; ++it) {
                f32x4 s = {0.f,0.f,0.f,0.f};
                short8 a0 = *(const short8*)&Kst[nb][(it*16 + l15) * 72 + quad*8];
                s = __builtin_amdgcn_mfma_f32_16x16x32_bf16(a0, qf0, s, 0, 0, 0);
                short8 a1 = *(const short8*)&Kst[nb][(it*16 + l15) * 72 + 32 + quad*8];
                s = __builtin_amdgcn_mfma_f32_16x16x32_bf16(a1, qf1, s, 0, 0, 0);
                f32x4 sp = {0.f,0.f,0.f,0.f};
                if (haspad) sp = *(const f32x4*)&spadf[nb][it*16 + quad*4];
                #pragma unroll
                for (int r = 0; r < 4; ++r) {
                    float v = __builtin_fmaf(s[r], SCALE, sp[r]);
                    if (needC && (i0 + it*16 + quad*4 + r > jg)) v += MASKV;
                    sv[it*4 + r] = v;
                }
            }
            __builtin_amdgcn_s_setprio(0);

            // online softmax over i (per j = l15; i spans regs + quads)
            float mt = sv[0];
            #pragma unroll
            for (int k = 1; k < 16; ++k) mt = fmaxf(mt, sv[k]);
            mt = fmaxf(mt, __shfl_xor(mt, 16));
            mt = fmaxf(mt, __shfl_xor(mt, 32));
            const float mnew  = fmaxf(m, mt);
            const float alpha = exp2f(m - mnew);
            float p[16], ls = 0.f;
            #pragma unroll
            for (int k = 0; k < 16; ++k) {
                p[k] = exp2f(sv[k] - mnew);
                ls += p[k];
            }
            ls += __shfl_xor(ls, 16);
            ls += __shfl_xor(ls, 32);
            l = l * alpha + ls;
            m = mnew;
            o0 *= alpha; o1 *= alpha; o2 *= alpha; o3 *= alpha;

            // PV B-frags directly from registers (V columns pre-permuted)
            short8 pf0, pf1;
            #pragma unroll
            for (int e = 0; e < 8; ++e) {
                pf0[e] = (short)f2bf(p[e]);
                pf1[e] = (short)f2bf(p[8 + e]);
            }
            short8 a;
            __builtin_amdgcn_s_setprio(1);
            a = *(const short8*)&VTst[nb][(     l15) * 72 +      quad * 8];
            o0 = __builtin_amdgcn_mfma_f32_16x16x32_bf16(a, pf0, o0, 0, 0, 0);
            a = *(const short8*)&VTst[nb][(     l15) * 72 + 32 + quad * 8];
            o0 = __builtin_amdgcn_mfma_f32_16x16x32_bf16(a, pf1, o0, 0, 0, 0);
            a = *(const short8*)&VTst[nb][(16 + l15) * 72 +      quad * 8];
            o1 = __builtin_amdgcn_mfma_f32_16x16x32_bf16(a, pf0, o1, 0, 0, 0);
            a = *(const short8*)&VTst[nb][(16 + l15) * 72 + 32 + quad * 8];
            o1 = __builtin_amdgcn_mfma_f32_16x16x32_bf16(a, pf1, o1, 0, 0, 0);
            a = *(const short8*)&VTst[nb][(32 + l15) * 72 +      quad * 8];
            o2 = __builtin_amdgcn_mfma_f32_16x16x32_bf16(a, pf0, o2, 0, 0, 0);
            a = *(const short8*)&VTst[nb][(32 + l15) * 72 + 32 + quad * 8];
            o2 = __builtin_amdgcn_mfma_f32_16x16x32_bf16(a, pf1, o2, 0, 0, 0);
            a = *(const short8*)&VTst[nb][(48 + l15) * 72 +      quad * 8];
            o3 = __builtin_amdgcn_mfma_f32_16x16x32_bf16(a, pf0, o3, 0, 0, 0);
            a = *(const short8*)&VTst[nb][(48 + l15) * 72 + 32 + quad * 8];
            o3 = __builtin_amdgcn_mfma_f32_16x16x32_bf16(a, pf1, o3, 0, 0, 0);
            __builtin_amdgcn_s_setprio(0);
        }

        if (tnext < 0) break;

        // ---- write next tile into the other buffer (T14 late-write) ----
        const int nb2 = nb ^ 1;
        *(short8*)&Kst[nb2][sk_row * 72 + sk_c * 8] = kreg;
        #pragma unroll
        for (int e = 0; e < 8; ++e)
            VTst[nb2][(sv_ch * 8 + e) * 72 + sv_col] = (unsigned short)vreg[e];
        if (tid < 64) spadf[nb2][tid] = (ksv == -1) ? MASKV : 0.f;
        __syncthreads();                     // single barrier per tile
        tcur = tnext; nb = nb2;
    }

    // epilogue: lane j = jg, d = dblk*16 + quad*4 + r -> float4 stores
    const float inv = 1.f / l;
    float* op = out + ((size_t)b * T_SZ + jg) * (N_H * D_H) + h * D_H + quad * 4;
    *(f32x4*)(op +  0) = o0 * inv;
    *(f32x4*)(op + 16) = o1 * inv;
    *(f32x4*)(op + 32) = o2 * inv;
    *(f32x4*)(op + 48) = o3 * inv;
}

// ---------------------------------------------------------------------------
extern "C" void kernel_launch(void* const* d_in, const int* in_sizes, int n_in,
                              void* d_out, int out_size, void* d_ws, size_t ws_size,
                              hipStream_t stream) {
    const float* keys    = (const float*)d_in[0];
    const float* queries = (const float*)d_in[1];
    const float* values  = (const float*)d_in[2];
    const float* Wk      = (const float*)d_in[3];
    const float* Wq      = (const float*)d_in[4];
    const float* Wv      = (const float*)d_in[5];
    const int*   key_seq = (const int*)d_in[6];

    const size_t per = (size_t)B_SZ * N_H * T_SZ * D_H;     // 4,194,304 elems
    unsigned short* KQVb = (unsigned short*)d_ws;            // K | Q | V bf16
    unsigned short* Kb = KQVb;
    unsigned short* Qb = KQVb + per;
    unsigned short* Vb = KQVb + 2 * per;
    unsigned short* Wt = KQVb + 3 * per;                     // 3*512*512 bf16

    wt_kernel<<<dim3(512 * 512 / 256, 3), 256, 0, stream>>>(Wk, Wq, Wv, Wt);
    proj_kernel<<<dim3(64, 4, 3), 256, 0, stream>>>(
        keys, queries, values, Wt, KQVb);
    attn_kernel<<<dim3(512), dim3(512), 0, stream>>>(
        Qb, Kb, Vb, key_seq, (float*)d_out);
}